// Round 4
// baseline (251.873 us; speedup 1.0000x reference)
//
#include <hip/hip_runtime.h>
#include <hip/hip_bf16.h>
#include <stdint.h>

// SparseSwiGLU on MI355X: gather-style densify (scan-select, no atomics, no
// sort) -> bf16 dense weights, then MFMA GEMMs.
// T=512 tokens, DIM=1024, HIDDEN=4096, NNZ=262144 per matrix.
//
// Workspace layout (<= 38 MB):
//   [0,    8MB)  WUP    bf16 [4096][1024]   (B^T for up GEMM, K-contiguous)
//   [8MB, 16MB)  WGATE  bf16 [4096][1024]
//   [16MB,24MB)  WDOWN  bf16 [1024][4096]
//   [24MB,25MB)  XB     bf16 [512][1024]
//   [25MB,29MB)  HID    bf16 [512][4096]
//   [29MB,30.5M) R16    u16 rows, 3 x 262144  (up, gate, down)
//   [31MB,37MB)  CV     uint2 (col, valbits), 3 x 262144

#define DIM_    1024
#define HIDDEN_ 4096
#define NNZ_    262144
#define TTOK_   512

typedef __attribute__((ext_vector_type(8))) short short8;
typedef __attribute__((ext_vector_type(4))) float float4v;

__device__ inline unsigned short f2bf(float f) {
    union { float f; unsigned int u; } c; c.f = f;
    unsigned int u = c.u;
    unsigned int r = u + 0x7fffu + ((u >> 16) & 1u);   // RNE
    return (unsigned short)(r >> 16);
}

__device__ inline void async16(const unsigned short* g, unsigned short* l) {
    __builtin_amdgcn_global_load_lds(
        (const __attribute__((address_space(1))) unsigned int*)g,
        (__attribute__((address_space(3))) unsigned int*)l, 16, 0, 0);
}

// ---------------------------------------------------------------- prep_pack
// [0,XC):      x -> bf16 (float4/thread)
// [XC,2XC):    out = x + down_bias
// [2XC,+RP):   pack row indices to u16 (8/thread)
// [2XC+RP,+CP): pack (col,val) to uint2 (4/thread)
#define XC_ ((TTOK_ * DIM_) / 4)           // 131072
#define RPM_ (NNZ_ / 8)                    // 32768 per matrix
#define CPM_ (NNZ_ / 4)                    // 65536 per matrix

__global__ void prep_pack_kernel(const float* __restrict__ x,
                                 const float* __restrict__ down_bias,
                                 const int* __restrict__ ur, const int* __restrict__ gr,
                                 const int* __restrict__ dr,
                                 const int* __restrict__ uc, const int* __restrict__ gc,
                                 const int* __restrict__ dc,
                                 const float* __restrict__ uv, const float* __restrict__ gv,
                                 const float* __restrict__ dv,
                                 unsigned short* __restrict__ xb,
                                 float* __restrict__ out,
                                 unsigned short* __restrict__ r16,
                                 uint2* __restrict__ cv) {
    unsigned int id = blockIdx.x * blockDim.x + threadIdx.x;
    if (id < XC_) {
        float4 v = ((const float4*)x)[id];
        ushort4 o;
        o.x = f2bf(v.x); o.y = f2bf(v.y); o.z = f2bf(v.z); o.w = f2bf(v.w);
        ((ushort4*)xb)[id] = o;
    } else if (id < 2u * XC_) {
        unsigned int i = id - XC_;
        float4 v = ((const float4*)x)[i];
        int d = (i * 4) & (DIM_ - 1);
        const float4 b = *(const float4*)(down_bias + d);
        float4 o;
        o.x = v.x + b.x; o.y = v.y + b.y; o.z = v.z + b.z; o.w = v.w + b.w;
        ((float4*)out)[i] = o;
    } else if (id < 2u * XC_ + 3u * RPM_) {
        unsigned int j = id - 2u * XC_;
        int mat = j / RPM_;
        unsigned int lj = j - mat * RPM_;
        const int* src = (mat == 0) ? ur : (mat == 1) ? gr : dr;
        const int4* a = (const int4*)src;
        int4 r0 = a[lj * 2], r1 = a[lj * 2 + 1];
        short8 o;
        o[0] = (short)r0.x; o[1] = (short)r0.y; o[2] = (short)r0.z; o[3] = (short)r0.w;
        o[4] = (short)r1.x; o[5] = (short)r1.y; o[6] = (short)r1.z; o[7] = (short)r1.w;
        *(short8*)(r16 + mat * NNZ_ + lj * 8) = o;
    } else if (id < 2u * XC_ + 3u * RPM_ + 3u * CPM_) {
        unsigned int j = id - 2u * XC_ - 3u * RPM_;
        int mat = j / CPM_;
        unsigned int lj = j - mat * CPM_;
        const int*   cs = (mat == 0) ? uc : (mat == 1) ? gc : dc;
        const float* vs = (mat == 0) ? uv : (mat == 1) ? gv : dv;
        int4 c4 = ((const int4*)cs)[lj];
        float4 v4 = ((const float4*)vs)[lj];
        uint2* dst = cv + mat * NNZ_ + lj * 4;
        uint4 w0, w1;
        w0.x = (unsigned int)c4.x; w0.y = __float_as_uint(v4.x);
        w0.z = (unsigned int)c4.y; w0.w = __float_as_uint(v4.y);
        w1.x = (unsigned int)c4.z; w1.y = __float_as_uint(v4.z);
        w1.z = (unsigned int)c4.w; w1.w = __float_as_uint(v4.w);
        *(uint4*)dst = w0;
        *(uint4*)(dst + 2) = w1;
    }
}

// ---------------------------------------------------------------- build
// One block owns a band of output rows (16 up/gate rows or 4 down rows =
// 16384 fp32 LDS cells either way). Scans its matrix's full u16 row array
// (512 KB, L2-resident, read-only shared), gathers (col,val) for the ~1K
// matches, LDS fp32 accumulate (duplicates exact), streams bf16 band out.
// No global atomics; every output cell written exactly once.
__global__ __launch_bounds__(512) void build_kernel(
    const unsigned short* __restrict__ r16,
    const uint2* __restrict__ cv,
    unsigned short* __restrict__ WUP,
    unsigned short* __restrict__ WGATE,
    unsigned short* __restrict__ WDOWN) {
    __shared__ float acc[16 * 1024];
    const int b = blockIdx.x;
    const int t = threadIdx.x;
    int mat, rbase;
    unsigned int nrows, width;
    unsigned short* out;
    if (b < 256)      { mat = 0; nrows = 16; width = 1024; rbase = b * 16;          out = WUP + rbase * 1024; }
    else if (b < 512) { mat = 1; nrows = 16; width = 1024; rbase = (b - 256) * 16;  out = WGATE + rbase * 1024; }
    else              { mat = 2; nrows = 4;  width = 4096; rbase = (b - 512) * 4;   out = WDOWN + rbase * 4096; }
    const unsigned short* R = r16 + mat * NNZ_;
    const uint2* C = cv + mat * NNZ_;

    for (int k = 0; k < 8; ++k)
        *(float4*)&acc[(k * 512 + t) * 4] = make_float4(0.f, 0.f, 0.f, 0.f);
    __syncthreads();

    for (int k = 0; k < 64; ++k) {
        const int v = k * 512 + t;
        short8 rr = *(const short8*)(R + v * 8);
        #pragma unroll
        for (int j = 0; j < 8; ++j) {
            const unsigned int row = (unsigned int)(unsigned short)rr[j] - rbase;
            if (row < nrows) {
                uint2 e = C[v * 8 + j];
                atomicAdd(&acc[row * width + e.x], __uint_as_float(e.y));
            }
        }
    }
    __syncthreads();

    for (int k = 0; k < 8; ++k) {
        const int c = (k * 512 + t) * 4;
        ushort4 o;
        o.x = f2bf(acc[c]);     o.y = f2bf(acc[c + 1]);
        o.z = f2bf(acc[c + 2]); o.w = f2bf(acc[c + 3]);
        *(ushort4*)(out + c) = o;
    }
}

// ---------------------------------------------------------------- up+gate GEMM
// C[512][4096] tiles 64(M)x128(N), BK=32, 256 thr = 4 waves, wave-tile 32x64.
// Two K-passes (up then gate) reuse the block; epilogue: silu(u)*g -> HID bf16.
__global__ __launch_bounds__(256) void gemm_upgate_kernel(
    const unsigned short* __restrict__ xb,      // [512][1024]
    const unsigned short* __restrict__ wup,     // [4096][1024]
    const unsigned short* __restrict__ wgate,   // [4096][1024]
    const float* __restrict__ up_bias,
    const float* __restrict__ gate_bias,
    unsigned short* __restrict__ hid) {         // [512][4096]
    __shared__ unsigned short sA[64 * 32];
    __shared__ unsigned short sB[128 * 32];
    const int t = threadIdx.x;
    const int m0 = blockIdx.y * 64;
    const int n0 = blockIdx.x * 128;
    const int w = t >> 6, l = t & 63;
    const int wm = (w >> 1) * 32, wn = (w & 1) * 64;
    const int lr = l & 15, lkq = (l >> 4);

    float4v acc[2][2][4];
    for (int p = 0; p < 2; ++p)
        for (int im = 0; im < 2; ++im)
            for (int in = 0; in < 4; ++in)
                acc[p][im][in] = float4v{0.f, 0.f, 0.f, 0.f};

    const int srow = t >> 2, scol = (t & 3) * 8;

    for (int p = 0; p < 2; ++p) {
        const unsigned short* W = p ? wgate : wup;
        for (int k0 = 0; k0 < DIM_; k0 += 32) {
            async16(xb + (m0 + srow) * DIM_ + k0 + scol, &sA[t * 8]);
            async16(W + (n0 + srow) * DIM_ + k0 + scol, &sB[t * 8]);
            async16(W + (n0 + 64 + srow) * DIM_ + k0 + scol, &sB[(t + 256) * 8]);
            __syncthreads();
            short8 a[2], b[4];
            for (int im = 0; im < 2; ++im)
                a[im] = *(const short8*)&sA[(wm + im * 16 + lr) * 32 + lkq * 8];
            for (int in = 0; in < 4; ++in)
                b[in] = *(const short8*)&sB[(wn + in * 16 + lr) * 32 + lkq * 8];
            for (int im = 0; im < 2; ++im)
                for (int in = 0; in < 4; ++in)
                    acc[p][im][in] = __builtin_amdgcn_mfma_f32_16x16x32_bf16(
                        a[im], b[in], acc[p][im][in], 0, 0, 0);
            __syncthreads();
        }
    }

    for (int im = 0; im < 2; ++im) {
        for (int in = 0; in < 4; ++in) {
            const int n = n0 + wn + in * 16 + lr;
            const float ub = up_bias[n], gb = gate_bias[n];
            for (int r = 0; r < 4; ++r) {
                const int m = m0 + wm + im * 16 + lkq * 4 + r;
                const float u = acc[0][im][in][r] + ub;
                const float g = acc[1][im][in][r] + gb;
                const float h = (u / (1.f + __expf(-u))) * g;
                hid[m * HIDDEN_ + n] = f2bf(h);
            }
        }
    }
}

// ---------------------------------------------------------------- down GEMM
// C[512][1024] tiles 64x64, split-K=4, atomicAdd epilogue onto d_out
// (pre-initialized to x + down_bias by prep_pack).
__global__ __launch_bounds__(256) void gemm_down_kernel(
    const unsigned short* __restrict__ hid,     // [512][4096]
    const unsigned short* __restrict__ wdown,   // [1024][4096]
    float* __restrict__ out) {                  // [512][1024]
    __shared__ unsigned short sA[64 * 32];
    __shared__ unsigned short sB[64 * 32];
    const int t = threadIdx.x;
    const int n0 = blockIdx.x * 64;
    const int m0 = blockIdx.y * 64;
    const int kb = blockIdx.z * 1024;
    const int w = t >> 6, l = t & 63;
    const int wm = (w >> 1) * 32, wn = (w & 1) * 32;
    const int lr = l & 15, lkq = (l >> 4);

    float4v acc[2][2];
    for (int im = 0; im < 2; ++im)
        for (int in = 0; in < 2; ++in)
            acc[im][in] = float4v{0.f, 0.f, 0.f, 0.f};

    const int srow = t >> 2, scol = (t & 3) * 8;

    for (int k0 = kb; k0 < kb + 1024; k0 += 32) {
        async16(hid + (m0 + srow) * HIDDEN_ + k0 + scol, &sA[t * 8]);
        async16(wdown + (n0 + srow) * HIDDEN_ + k0 + scol, &sB[t * 8]);
        __syncthreads();
        short8 a[2], b[2];
        for (int im = 0; im < 2; ++im)
            a[im] = *(const short8*)&sA[(wm + im * 16 + lr) * 32 + lkq * 8];
        for (int in = 0; in < 2; ++in)
            b[in] = *(const short8*)&sB[(wn + in * 16 + lr) * 32 + lkq * 8];
        for (int im = 0; im < 2; ++im)
            for (int in = 0; in < 2; ++in)
                acc[im][in] = __builtin_amdgcn_mfma_f32_16x16x32_bf16(
                    a[im], b[in], acc[im][in], 0, 0, 0);
        __syncthreads();
    }

    for (int im = 0; im < 2; ++im) {
        for (int in = 0; in < 2; ++in) {
            const int n = n0 + wn + in * 16 + lr;
            for (int r = 0; r < 4; ++r) {
                const int m = m0 + wm + im * 16 + lkq * 4 + r;
                atomicAdd(out + m * DIM_ + n, acc[im][in][r]);
            }
        }
    }
}

// ---------------------------------------------------------------- launch
extern "C" void kernel_launch(void* const* d_in, const int* in_sizes, int n_in,
                              void* d_out, int out_size, void* d_ws, size_t ws_size,
                              hipStream_t stream) {
    const float* x         = (const float*)d_in[0];
    const int*   up_row    = (const int*)d_in[1];
    const int*   up_col    = (const int*)d_in[2];
    const float* up_val    = (const float*)d_in[3];
    const float* up_bias   = (const float*)d_in[4];
    const int*   gate_row  = (const int*)d_in[5];
    const int*   gate_col  = (const int*)d_in[6];
    const float* gate_val  = (const float*)d_in[7];
    const float* gate_bias = (const float*)d_in[8];
    const int*   down_row  = (const int*)d_in[9];
    const int*   down_col  = (const int*)d_in[10];
    const float* down_val  = (const float*)d_in[11];
    const float* down_bias = (const float*)d_in[12];
    float* out = (float*)d_out;

    unsigned char* ws = (unsigned char*)d_ws;
    unsigned short* WUP   = (unsigned short*)(ws);
    unsigned short* WGATE = (unsigned short*)(ws + (8u << 20));
    unsigned short* WDOWN = (unsigned short*)(ws + (16u << 20));
    unsigned short* XB    = (unsigned short*)(ws + (24u << 20));
    unsigned short* HID   = (unsigned short*)(ws + (25u << 20));
    unsigned short* R16   = (unsigned short*)(ws + (29u << 20));
    uint2*          CV    = (uint2*)(ws + (31u << 20));

    // 2*XC + 3*RPM + 3*CPM = 262144 + 294912 = 557056 = 2176 * 256
    prep_pack_kernel<<<2176, 256, 0, stream>>>(
        x, down_bias, up_row, gate_row, down_row,
        up_col, gate_col, down_col, up_val, gate_val, down_val,
        XB, out, R16, CV);

    build_kernel<<<768, 512, 0, stream>>>(R16, CV, WUP, WGATE, WDOWN);

    gemm_upgate_kernel<<<dim3(HIDDEN_ / 128, TTOK_ / 64), 256, 0, stream>>>(
        XB, WUP, WGATE, up_bias, gate_bias, HID);

    gemm_down_kernel<<<dim3(DIM_ / 64, TTOK_ / 64, 4), 256, 0, stream>>>(
        HID, WDOWN, out);
}

// Round 5
// 198.087 us; speedup vs baseline: 1.2715x; 1.2715x over previous
//
#include <hip/hip_runtime.h>
#include <hip/hip_bf16.h>
#include <stdint.h>

// SparseSwiGLU on MI355X: radix-bin densify (block-local padded bins, no
// global atomics) -> bf16 dense weights, then MFMA GEMMs.
// T=512 tokens, DIM=1024, HIDDEN=4096, NNZ=262144 per matrix.
//
// Workspace layout (<= 42 MB):
//   [0,    8MB)  WUP    bf16 [4096][1024]   (B^T for up GEMM, K-contiguous)
//   [8MB, 16MB)  WGATE  bf16 [4096][1024]
//   [16MB,24MB)  WDOWN  bf16 [1024][4096]
//   [24MB,25MB)  XB     bf16 [512][1024]
//   [25MB,29MB)  HID    bf16 [512][4096]
//   [29MB,41MB)  BANDS  uint2[3][16 bands][256 chunks][128 slots]  (12 MB)
//   [41MB,+48KB) CNT    int[3][16][256]

#define DIM_    1024
#define HIDDEN_ 4096
#define NNZ_    262144
#define TTOK_   512

typedef __attribute__((ext_vector_type(8))) short short8;
typedef __attribute__((ext_vector_type(4))) float float4v;

__device__ inline unsigned short f2bf(float f) {
    union { float f; unsigned int u; } c; c.f = f;
    unsigned int u = c.u;
    unsigned int r = u + 0x7fffu + ((u >> 16) & 1u);   // RNE
    return (unsigned short)(r >> 16);
}

__device__ inline void async16(const unsigned short* g, unsigned short* l) {
    __builtin_amdgcn_global_load_lds(
        (const __attribute__((address_space(1))) unsigned int*)g,
        (__attribute__((address_space(3))) unsigned int*)l, 16, 0, 0);
}

// ---------------------------------------------------------------- prep
// [0,XC): x -> bf16 (float4/thread); [XC,2XC): out = x + down_bias.
#define XC_ ((TTOK_ * DIM_) / 4)           // 131072

__global__ void prep_kernel(const float* __restrict__ x,
                            const float* __restrict__ down_bias,
                            unsigned short* __restrict__ xb,
                            float* __restrict__ out) {
    unsigned int id = blockIdx.x * blockDim.x + threadIdx.x;
    if (id < XC_) {
        float4 v = ((const float4*)x)[id];
        ushort4 o;
        o.x = f2bf(v.x); o.y = f2bf(v.y); o.z = f2bf(v.z); o.w = f2bf(v.w);
        ((ushort4*)xb)[id] = o;
    } else {
        unsigned int i = id - XC_;
        float4 v = ((const float4*)x)[i];
        int d = (i * 4) & (DIM_ - 1);
        const float4 b = *(const float4*)(down_bias + d);
        float4 o;
        o.x = v.x + b.x; o.y = v.y + b.y; o.z = v.z + b.z; o.w = v.w + b.w;
        ((float4*)out)[i] = o;
    }
}

// ---------------------------------------------------------------- bin
// 768 blocks x 256 thr; block = (mat, chunk of 1024 nnz). Classify entries
// by row-band (16 bands/matrix) and write (row<<12|col, valbits) into the
// block's OWN padded sub-region of each band: no global atomics, writes are
// 1KB-granular single-writer (no cross-XCD line bouncing). Counts -> CNT.
// Per-(chunk,band) count: mean 64, sigma 7.75; PAD=128 is +8 sigma.
#define PAD_ 128

__global__ __launch_bounds__(256) void bin_kernel(
    const int* __restrict__ ur, const int* __restrict__ uc, const float* __restrict__ uv,
    const int* __restrict__ gr, const int* __restrict__ gc, const float* __restrict__ gv,
    const int* __restrict__ dr, const int* __restrict__ dc, const float* __restrict__ dv,
    uint2* __restrict__ bands, int* __restrict__ cnt) {
    __shared__ int lcount[16];
    const int b = blockIdx.x;
    const int t = threadIdx.x;
    const int mat = b >> 8;          // 0 up, 1 gate, 2 down
    const int chunk = b & 255;
    const int*   rs = (mat == 0) ? ur : (mat == 1) ? gr : dr;
    const int*   cs = (mat == 0) ? uc : (mat == 1) ? gc : dc;
    const float* vs = (mat == 0) ? uv : (mat == 1) ? gv : dv;
    const int shift = (mat == 2) ? 6 : 8;   // 64 rows/band (down), 256 (up/gate)
    if (t < 16) lcount[t] = 0;
    __syncthreads();

    const int base = chunk * 1024 + t * 4;
    int4   r4 = *(const int4*)(rs + base);
    int4   c4 = *(const int4*)(cs + base);
    float4 v4 = *(const float4*)(vs + base);
    uint2* mbase = bands + mat * (16 * 256 * PAD_);
    int   rr[4] = {r4.x, r4.y, r4.z, r4.w};
    int   cc[4] = {c4.x, c4.y, c4.z, c4.w};
    float vv[4] = {v4.x, v4.y, v4.z, v4.w};
    #pragma unroll
    for (int j = 0; j < 4; ++j) {
        int band = rr[j] >> shift;
        int pos = atomicAdd(&lcount[band], 1);
        if (pos < PAD_) {   // statistically impossible to fail; guards corruption
            uint2 e;
            e.x = ((unsigned int)rr[j] << 12) | (unsigned int)cc[j];
            e.y = __float_as_uint(vv[j]);
            mbase[band * (256 * PAD_) + chunk * PAD_ + pos] = e;
        }
    }
    __syncthreads();
    if (t < 16) cnt[mat * 4096 + t * 256 + chunk] = lcount[t];
}

// ---------------------------------------------------------------- build
// One block = 16 up/gate rows or 4 down rows (64KB fp32 LDS). Scans ONLY its
// band's region (256KB padded, ~131KB valid): unconditional-address pipelined
// loads, rare LDS fp32 atomic per match, streams bf16 rows out once.
__global__ __launch_bounds__(512) void build_kernel(
    const uint2* __restrict__ bands,
    const int* __restrict__ cnt,
    unsigned short* __restrict__ WUP,
    unsigned short* __restrict__ WGATE,
    unsigned short* __restrict__ WDOWN) {
    __shared__ float acc[16 * 1024];
    __shared__ int lcnt[256];
    const int b = blockIdx.x;
    const int t = threadIdx.x;
    int mat, rbase;
    unsigned int nrows, width;
    unsigned short* out;
    if (b < 256)      { mat = 0; nrows = 16; width = 1024; rbase = b * 16;         out = WUP + rbase * 1024; }
    else if (b < 512) { mat = 1; nrows = 16; width = 1024; rbase = (b - 256) * 16; out = WGATE + rbase * 1024; }
    else              { mat = 2; nrows = 4;  width = 4096; rbase = (b - 512) * 4;  out = WDOWN + rbase * 4096; }
    const int band = (b & 255) >> 4;        // 16 build blocks per band
    const uint2* B = bands + mat * (16 * 256 * PAD_) + band * (256 * PAD_);
    const int*   C = cnt + mat * 4096 + band * 256;

    for (int k = 0; k < 8; ++k)
        *(float4*)&acc[(k * 512 + t) * 4] = make_float4(0.f, 0.f, 0.f, 0.f);
    if (t < 256) lcnt[t] = C[t];
    __syncthreads();

    #pragma unroll 4
    for (int i = 0; i < 64; ++i) {
        const int s = i * 512 + t;
        const int chunk = s >> 7, slot = s & (PAD_ - 1);
        if (slot < lcnt[chunk]) {
            uint2 e = B[s];
            unsigned int rrel = (e.x >> 12) - rbase;   // unsigned wrap rejects other rows
            if (rrel < nrows)
                atomicAdd(&acc[rrel * width + (e.x & 0xFFFu)], __uint_as_float(e.y));
        }
    }
    __syncthreads();

    for (int k = 0; k < 8; ++k) {
        const int c = (k * 512 + t) * 4;
        ushort4 o;
        o.x = f2bf(acc[c]);     o.y = f2bf(acc[c + 1]);
        o.z = f2bf(acc[c + 2]); o.w = f2bf(acc[c + 3]);
        *(ushort4*)(out + c) = o;
    }
}

// ---------------------------------------------------------------- up+gate GEMM
// C[512][4096] tiles 64(M)x128(N), BK=32, 256 thr = 4 waves, wave-tile 32x64.
// Two K-passes (up then gate) reuse the block; epilogue: silu(u)*g -> HID bf16.
__global__ __launch_bounds__(256) void gemm_upgate_kernel(
    const unsigned short* __restrict__ xb,      // [512][1024]
    const unsigned short* __restrict__ wup,     // [4096][1024]
    const unsigned short* __restrict__ wgate,   // [4096][1024]
    const float* __restrict__ up_bias,
    const float* __restrict__ gate_bias,
    unsigned short* __restrict__ hid) {         // [512][4096]
    __shared__ unsigned short sA[64 * 32];
    __shared__ unsigned short sB[128 * 32];
    const int t = threadIdx.x;
    const int m0 = blockIdx.y * 64;
    const int n0 = blockIdx.x * 128;
    const int w = t >> 6, l = t & 63;
    const int wm = (w >> 1) * 32, wn = (w & 1) * 64;
    const int lr = l & 15, lkq = (l >> 4);

    float4v acc[2][2][4];
    for (int p = 0; p < 2; ++p)
        for (int im = 0; im < 2; ++im)
            for (int in = 0; in < 4; ++in)
                acc[p][im][in] = float4v{0.f, 0.f, 0.f, 0.f};

    const int srow = t >> 2, scol = (t & 3) * 8;

    for (int p = 0; p < 2; ++p) {
        const unsigned short* W = p ? wgate : wup;
        for (int k0 = 0; k0 < DIM_; k0 += 32) {
            async16(xb + (m0 + srow) * DIM_ + k0 + scol, &sA[t * 8]);
            async16(W + (n0 + srow) * DIM_ + k0 + scol, &sB[t * 8]);
            async16(W + (n0 + 64 + srow) * DIM_ + k0 + scol, &sB[(t + 256) * 8]);
            __syncthreads();
            short8 a[2], b[4];
            for (int im = 0; im < 2; ++im)
                a[im] = *(const short8*)&sA[(wm + im * 16 + lr) * 32 + lkq * 8];
            for (int in = 0; in < 4; ++in)
                b[in] = *(const short8*)&sB[(wn + in * 16 + lr) * 32 + lkq * 8];
            for (int im = 0; im < 2; ++im)
                for (int in = 0; in < 4; ++in)
                    acc[p][im][in] = __builtin_amdgcn_mfma_f32_16x16x32_bf16(
                        a[im], b[in], acc[p][im][in], 0, 0, 0);
            __syncthreads();
        }
    }

    for (int im = 0; im < 2; ++im) {
        for (int in = 0; in < 4; ++in) {
            const int n = n0 + wn + in * 16 + lr;
            const float ub = up_bias[n], gb = gate_bias[n];
            for (int r = 0; r < 4; ++r) {
                const int m = m0 + wm + im * 16 + lkq * 4 + r;
                const float u = acc[0][im][in][r] + ub;
                const float g = acc[1][im][in][r] + gb;
                const float h = (u / (1.f + __expf(-u))) * g;
                hid[m * HIDDEN_ + n] = f2bf(h);
            }
        }
    }
}

// ---------------------------------------------------------------- down GEMM
// C[512][1024] tiles 64x64, split-K=4, atomicAdd epilogue onto d_out
// (pre-initialized to x + down_bias by prep).
__global__ __launch_bounds__(256) void gemm_down_kernel(
    const unsigned short* __restrict__ hid,     // [512][4096]
    const unsigned short* __restrict__ wdown,   // [1024][4096]
    float* __restrict__ out) {                  // [512][1024]
    __shared__ unsigned short sA[64 * 32];
    __shared__ unsigned short sB[64 * 32];
    const int t = threadIdx.x;
    const int n0 = blockIdx.x * 64;
    const int m0 = blockIdx.y * 64;
    const int kb = blockIdx.z * 1024;
    const int w = t >> 6, l = t & 63;
    const int wm = (w >> 1) * 32, wn = (w & 1) * 32;
    const int lr = l & 15, lkq = (l >> 4);

    float4v acc[2][2];
    for (int im = 0; im < 2; ++im)
        for (int in = 0; in < 2; ++in)
            acc[im][in] = float4v{0.f, 0.f, 0.f, 0.f};

    const int srow = t >> 2, scol = (t & 3) * 8;

    for (int k0 = kb; k0 < kb + 1024; k0 += 32) {
        async16(hid + (m0 + srow) * HIDDEN_ + k0 + scol, &sA[t * 8]);
        async16(wdown + (n0 + srow) * HIDDEN_ + k0 + scol, &sB[t * 8]);
        __syncthreads();
        short8 a[2], b[2];
        for (int im = 0; im < 2; ++im)
            a[im] = *(const short8*)&sA[(wm + im * 16 + lr) * 32 + lkq * 8];
        for (int in = 0; in < 2; ++in)
            b[in] = *(const short8*)&sB[(wn + in * 16 + lr) * 32 + lkq * 8];
        for (int im = 0; im < 2; ++im)
            for (int in = 0; in < 2; ++in)
                acc[im][in] = __builtin_amdgcn_mfma_f32_16x16x32_bf16(
                    a[im], b[in], acc[im][in], 0, 0, 0);
        __syncthreads();
    }

    for (int im = 0; im < 2; ++im) {
        for (int in = 0; in < 2; ++in) {
            const int n = n0 + wn + in * 16 + lr;
            for (int r = 0; r < 4; ++r) {
                const int m = m0 + wm + im * 16 + lkq * 4 + r;
                atomicAdd(out + m * DIM_ + n, acc[im][in][r]);
            }
        }
    }
}

// ---------------------------------------------------------------- launch
extern "C" void kernel_launch(void* const* d_in, const int* in_sizes, int n_in,
                              void* d_out, int out_size, void* d_ws, size_t ws_size,
                              hipStream_t stream) {
    const float* x         = (const float*)d_in[0];
    const int*   up_row    = (const int*)d_in[1];
    const int*   up_col    = (const int*)d_in[2];
    const float* up_val    = (const float*)d_in[3];
    const float* up_bias   = (const float*)d_in[4];
    const int*   gate_row  = (const int*)d_in[5];
    const int*   gate_col  = (const int*)d_in[6];
    const float* gate_val  = (const float*)d_in[7];
    const float* gate_bias = (const float*)d_in[8];
    const int*   down_row  = (const int*)d_in[9];
    const int*   down_col  = (const int*)d_in[10];
    const float* down_val  = (const float*)d_in[11];
    const float* down_bias = (const float*)d_in[12];
    float* out = (float*)d_out;

    unsigned char* ws = (unsigned char*)d_ws;
    unsigned short* WUP   = (unsigned short*)(ws);
    unsigned short* WGATE = (unsigned short*)(ws + (8u << 20));
    unsigned short* WDOWN = (unsigned short*)(ws + (16u << 20));
    unsigned short* XB    = (unsigned short*)(ws + (24u << 20));
    unsigned short* HID   = (unsigned short*)(ws + (25u << 20));
    uint2*          BANDS = (uint2*)(ws + (29u << 20));
    int*            CNT   = (int*)(ws + (41u << 20));

    // 2*XC = 262144 = 1024 * 256
    prep_kernel<<<1024, 256, 0, stream>>>(x, down_bias, XB, out);

    bin_kernel<<<768, 256, 0, stream>>>(
        up_row, up_col, up_val, gate_row, gate_col, gate_val,
        down_row, down_col, down_val, BANDS, CNT);

    build_kernel<<<768, 512, 0, stream>>>(BANDS, CNT, WUP, WGATE, WDOWN);

    gemm_upgate_kernel<<<dim3(HIDDEN_ / 128, TTOK_ / 64), 256, 0, stream>>>(
        XB, WUP, WGATE, up_bias, gate_bias, HID);

    gemm_down_kernel<<<dim3(DIM_ / 64, TTOK_ / 64, 4), 256, 0, stream>>>(
        HID, WDOWN, out);
}

// Round 6
// 154.240 us; speedup vs baseline: 1.6330x; 1.2843x over previous
//
#include <hip/hip_runtime.h>
#include <hip/hip_bf16.h>
#include <stdint.h>

// SparseSwiGLU on MI355X: fine-band radix densify (1 band == 1 build block,
// batched unconditional loads, no global atomics) -> bf16 weights -> MFMA GEMMs.
// T=512 tokens, DIM=1024, HIDDEN=4096, NNZ=262144 per matrix.
//
// Workspace layout (<= 67 MB):
//   [0,    8MB)  WUP    bf16 [4096][1024]   (B^T for up GEMM, K-contiguous)
//   [8MB, 16MB)  WGATE  bf16 [4096][1024]
//   [16MB,24MB)  WDOWN  bf16 [1024][4096]
//   [24MB,25MB)  XB     bf16 [512][1024]
//   [25MB,29MB)  HID    bf16 [512][4096]
//   [29MB,+36MB) BANDS  uint2[3][256 band][256 chunk][24 slot]  (37.75 MB)
//   [66MB,+768K) CNT    int[3][256 band][256 chunk]

#define DIM_    1024
#define HIDDEN_ 4096
#define NNZ_    262144
#define TTOK_   512
#define PAD_    24              // 192 B = 3 cache lines, single-writer segments

typedef __attribute__((ext_vector_type(8))) short short8;
typedef __attribute__((ext_vector_type(4))) float float4v;

__device__ inline unsigned short f2bf(float f) {
    union { float f; unsigned int u; } c; c.f = f;
    unsigned int u = c.u;
    unsigned int r = u + 0x7fffu + ((u >> 16) & 1u);   // RNE
    return (unsigned short)(r >> 16);
}

__device__ inline void async16(const unsigned short* g, unsigned short* l) {
    __builtin_amdgcn_global_load_lds(
        (const __attribute__((address_space(1))) unsigned int*)g,
        (__attribute__((address_space(3))) unsigned int*)l, 16, 0, 0);
}

// ---------------------------------------------------------------- prep
// [0,XC): x -> bf16 (float4/thread); [XC,2XC): out = x + down_bias.
#define XC_ ((TTOK_ * DIM_) / 4)           // 131072

__global__ void prep_kernel(const float* __restrict__ x,
                            const float* __restrict__ down_bias,
                            unsigned short* __restrict__ xb,
                            float* __restrict__ out) {
    unsigned int id = blockIdx.x * blockDim.x + threadIdx.x;
    if (id < XC_) {
        float4 v = ((const float4*)x)[id];
        ushort4 o;
        o.x = f2bf(v.x); o.y = f2bf(v.y); o.z = f2bf(v.z); o.w = f2bf(v.w);
        ((ushort4*)xb)[id] = o;
    } else {
        unsigned int i = id - XC_;
        float4 v = ((const float4*)x)[i];
        int d = (i * 4) & (DIM_ - 1);
        const float4 b = *(const float4*)(down_bias + d);
        float4 o;
        o.x = v.x + b.x; o.y = v.y + b.y; o.z = v.z + b.z; o.w = v.w + b.w;
        ((float4*)out)[i] = o;
    }
}

// ---------------------------------------------------------------- bin
// 768 blocks x 256 thr; block = (mat, chunk of 1024 nnz). 256 bands/matrix
// (16 rows up/gate, 4 rows down). Entry = (rrel<<12 | col, valbits) into the
// block's own 192B segment of each band. Counts -> CNT[mat][band][chunk].
// Per-(chunk,band) count ~ Poisson(4); PAD=24 overflow prob ~1e-11/bin.
__global__ __launch_bounds__(256) void bin_kernel(
    const int* __restrict__ ur, const int* __restrict__ uc, const float* __restrict__ uv,
    const int* __restrict__ gr, const int* __restrict__ gc, const float* __restrict__ gv,
    const int* __restrict__ dr, const int* __restrict__ dc, const float* __restrict__ dv,
    uint2* __restrict__ bands, int* __restrict__ cnt) {
    __shared__ int lcount[256];
    const int b = blockIdx.x;
    const int t = threadIdx.x;
    const int mat = b >> 8;          // 0 up, 1 gate, 2 down
    const int chunk = b & 255;
    const int*   rs = (mat == 0) ? ur : (mat == 1) ? gr : dr;
    const int*   cs = (mat == 0) ? uc : (mat == 1) ? gc : dc;
    const float* vs = (mat == 0) ? uv : (mat == 1) ? gv : dv;
    const int shift = (mat == 2) ? 2 : 4;   // rows/band: 4 (down), 16 (up/gate)
    const int rmask = (mat == 2) ? 3 : 15;
    lcount[t] = 0;
    __syncthreads();

    const int base = chunk * 1024 + t * 4;
    int4   r4 = *(const int4*)(rs + base);
    int4   c4 = *(const int4*)(cs + base);
    float4 v4 = *(const float4*)(vs + base);
    uint2* mbase = bands + mat * (256 * 256 * PAD_);
    int   rr[4] = {r4.x, r4.y, r4.z, r4.w};
    int   cc[4] = {c4.x, c4.y, c4.z, c4.w};
    float vv[4] = {v4.x, v4.y, v4.z, v4.w};
    #pragma unroll
    for (int j = 0; j < 4; ++j) {
        const int band = rr[j] >> shift;
        const int pos = atomicAdd(&lcount[band], 1);
        if (pos < PAD_) {
            uint2 e;
            e.x = ((unsigned int)(rr[j] & rmask) << 12) | (unsigned int)cc[j];
            e.y = __float_as_uint(vv[j]);
            mbase[(band * 256 + chunk) * PAD_ + pos] = e;
        }
    }
    __syncthreads();
    cnt[(mat * 256 + t) * 256 + chunk] = lcount[t];
}

// ---------------------------------------------------------------- build
// One block == one band (16 up/gate rows or 4 down rows; 64KB fp32 LDS).
// Thread pair per chunk: half 0 loads slots 0..11 UNCONDITIONALLY (6 dwordx4,
// one waitcnt; use guarded by count), half 1 handles the ~0.02% overflow tail.
// LDS fp32 accumulate absorbs duplicates; streams bf16 rows out once.
__global__ __launch_bounds__(512) void build_kernel(
    const uint2* __restrict__ bands,
    const int* __restrict__ cnt,
    unsigned short* __restrict__ WUP,
    unsigned short* __restrict__ WGATE,
    unsigned short* __restrict__ WDOWN) {
    __shared__ float acc[16 * 1024];
    __shared__ int lcnt[256];
    const int b = blockIdx.x;
    const int t = threadIdx.x;
    const int mat = b >> 8;
    const int band = b & 255;
    unsigned int width;
    unsigned short* out;
    if (mat == 0)      { width = 1024; out = WUP + band * 16 * 1024; }
    else if (mat == 1) { width = 1024; out = WGATE + band * 16 * 1024; }
    else               { width = 4096; out = WDOWN + band * 4 * 4096; }

    for (int k = 0; k < 8; ++k)
        *(float4*)&acc[(k * 512 + t) * 4] = make_float4(0.f, 0.f, 0.f, 0.f);
    if (t < 256) lcnt[t] = cnt[(mat * 256 + band) * 256 + t];
    __syncthreads();

    const int chunk = t & 255;
    const int half = t >> 8;
    const uint2* seg = bands + (((mat * 256 + band) * 256) + chunk) * PAD_;
    const int c = lcnt[chunk];

    if (half == 0) {
        // batch-load first 12 slots (96B contiguous) unconditionally
        uint4 q[6];
        const uint4* sp = (const uint4*)seg;
        #pragma unroll
        for (int i = 0; i < 6; ++i) q[i] = sp[i];
        #pragma unroll
        for (int j = 0; j < 12; ++j) {
            const unsigned int ex = (j & 1) ? q[j >> 1].z : q[j >> 1].x;
            const unsigned int ey = (j & 1) ? q[j >> 1].w : q[j >> 1].y;
            if (j < c)
                atomicAdd(&acc[(ex >> 12) * width + (ex & 0xFFFu)],
                          __uint_as_float(ey));
        }
    } else {
        for (int j = 12; j < c && j < PAD_; ++j) {   // ~0.02% of chunks
            uint2 e = seg[j];
            atomicAdd(&acc[(e.x >> 12) * width + (e.x & 0xFFFu)],
                      __uint_as_float(e.y));
        }
    }
    __syncthreads();

    for (int k = 0; k < 8; ++k) {
        const int cc = (k * 512 + t) * 4;
        ushort4 o;
        o.x = f2bf(acc[cc]);     o.y = f2bf(acc[cc + 1]);
        o.z = f2bf(acc[cc + 2]); o.w = f2bf(acc[cc + 3]);
        *(ushort4*)(out + cc) = o;
    }
}

// ---------------------------------------------------------------- up+gate GEMM
// C[512][4096] tiles 64(M)x128(N), BK=32, 256 thr = 4 waves, wave-tile 32x64.
// Two K-passes (up then gate) reuse the block; epilogue: silu(u)*g -> HID bf16.
__global__ __launch_bounds__(256) void gemm_upgate_kernel(
    const unsigned short* __restrict__ xb,      // [512][1024]
    const unsigned short* __restrict__ wup,     // [4096][1024]
    const unsigned short* __restrict__ wgate,   // [4096][1024]
    const float* __restrict__ up_bias,
    const float* __restrict__ gate_bias,
    unsigned short* __restrict__ hid) {         // [512][4096]
    __shared__ unsigned short sA[64 * 32];
    __shared__ unsigned short sB[128 * 32];
    const int t = threadIdx.x;
    const int m0 = blockIdx.y * 64;
    const int n0 = blockIdx.x * 128;
    const int w = t >> 6, l = t & 63;
    const int wm = (w >> 1) * 32, wn = (w & 1) * 64;
    const int lr = l & 15, lkq = (l >> 4);

    float4v acc[2][2][4];
    for (int p = 0; p < 2; ++p)
        for (int im = 0; im < 2; ++im)
            for (int in = 0; in < 4; ++in)
                acc[p][im][in] = float4v{0.f, 0.f, 0.f, 0.f};

    const int srow = t >> 2, scol = (t & 3) * 8;

    for (int p = 0; p < 2; ++p) {
        const unsigned short* W = p ? wgate : wup;
        for (int k0 = 0; k0 < DIM_; k0 += 32) {
            async16(xb + (m0 + srow) * DIM_ + k0 + scol, &sA[t * 8]);
            async16(W + (n0 + srow) * DIM_ + k0 + scol, &sB[t * 8]);
            async16(W + (n0 + 64 + srow) * DIM_ + k0 + scol, &sB[(t + 256) * 8]);
            __syncthreads();
            short8 a[2], b[4];
            for (int im = 0; im < 2; ++im)
                a[im] = *(const short8*)&sA[(wm + im * 16 + lr) * 32 + lkq * 8];
            for (int in = 0; in < 4; ++in)
                b[in] = *(const short8*)&sB[(wn + in * 16 + lr) * 32 + lkq * 8];
            for (int im = 0; im < 2; ++im)
                for (int in = 0; in < 4; ++in)
                    acc[p][im][in] = __builtin_amdgcn_mfma_f32_16x16x32_bf16(
                        a[im], b[in], acc[p][im][in], 0, 0, 0);
            __syncthreads();
        }
    }

    for (int im = 0; im < 2; ++im) {
        for (int in = 0; in < 4; ++in) {
            const int n = n0 + wn + in * 16 + lr;
            const float ub = up_bias[n], gb = gate_bias[n];
            for (int r = 0; r < 4; ++r) {
                const int m = m0 + wm + im * 16 + lkq * 4 + r;
                const float u = acc[0][im][in][r] + ub;
                const float g = acc[1][im][in][r] + gb;
                const float h = (u / (1.f + __expf(-u))) * g;
                hid[m * HIDDEN_ + n] = f2bf(h);
            }
        }
    }
}

// ---------------------------------------------------------------- down GEMM
// C[512][1024] tiles 64x64, split-K=4, atomicAdd epilogue onto d_out
// (pre-initialized to x + down_bias by prep).
__global__ __launch_bounds__(256) void gemm_down_kernel(
    const unsigned short* __restrict__ hid,     // [512][4096]
    const unsigned short* __restrict__ wdown,   // [1024][4096]
    float* __restrict__ out) {                  // [512][1024]
    __shared__ unsigned short sA[64 * 32];
    __shared__ unsigned short sB[64 * 32];
    const int t = threadIdx.x;
    const int n0 = blockIdx.x * 64;
    const int m0 = blockIdx.y * 64;
    const int kb = blockIdx.z * 1024;
    const int w = t >> 6, l = t & 63;
    const int wm = (w >> 1) * 32, wn = (w & 1) * 32;
    const int lr = l & 15, lkq = (l >> 4);

    float4v acc[2][2];
    for (int im = 0; im < 2; ++im)
        for (int in = 0; in < 2; ++in)
            acc[im][in] = float4v{0.f, 0.f, 0.f, 0.f};

    const int srow = t >> 2, scol = (t & 3) * 8;

    for (int k0 = kb; k0 < kb + 1024; k0 += 32) {
        async16(hid + (m0 + srow) * HIDDEN_ + k0 + scol, &sA[t * 8]);
        async16(wdown + (n0 + srow) * HIDDEN_ + k0 + scol, &sB[t * 8]);
        __syncthreads();
        short8 a[2], b[2];
        for (int im = 0; im < 2; ++im)
            a[im] = *(const short8*)&sA[(wm + im * 16 + lr) * 32 + lkq * 8];
        for (int in = 0; in < 2; ++in)
            b[in] = *(const short8*)&sB[(wn + in * 16 + lr) * 32 + lkq * 8];
        for (int im = 0; im < 2; ++im)
            for (int in = 0; in < 2; ++in)
                acc[im][in] = __builtin_amdgcn_mfma_f32_16x16x32_bf16(
                    a[im], b[in], acc[im][in], 0, 0, 0);
        __syncthreads();
    }

    for (int im = 0; im < 2; ++im) {
        for (int in = 0; in < 2; ++in) {
            const int n = n0 + wn + in * 16 + lr;
            for (int r = 0; r < 4; ++r) {
                const int m = m0 + wm + im * 16 + lkq * 4 + r;
                atomicAdd(out + m * DIM_ + n, acc[im][in][r]);
            }
        }
    }
}

// ---------------------------------------------------------------- launch
extern "C" void kernel_launch(void* const* d_in, const int* in_sizes, int n_in,
                              void* d_out, int out_size, void* d_ws, size_t ws_size,
                              hipStream_t stream) {
    const float* x         = (const float*)d_in[0];
    const int*   up_row    = (const int*)d_in[1];
    const int*   up_col    = (const int*)d_in[2];
    const float* up_val    = (const float*)d_in[3];
    const float* up_bias   = (const float*)d_in[4];
    const int*   gate_row  = (const int*)d_in[5];
    const int*   gate_col  = (const int*)d_in[6];
    const float* gate_val  = (const float*)d_in[7];
    const float* gate_bias = (const float*)d_in[8];
    const int*   down_row  = (const int*)d_in[9];
    const int*   down_col  = (const int*)d_in[10];
    const float* down_val  = (const float*)d_in[11];
    const float* down_bias = (const float*)d_in[12];
    float* out = (float*)d_out;

    unsigned char* ws = (unsigned char*)d_ws;
    unsigned short* WUP   = (unsigned short*)(ws);
    unsigned short* WGATE = (unsigned short*)(ws + (8u << 20));
    unsigned short* WDOWN = (unsigned short*)(ws + (16u << 20));
    unsigned short* XB    = (unsigned short*)(ws + (24u << 20));
    unsigned short* HID   = (unsigned short*)(ws + (25u << 20));
    uint2*          BANDS = (uint2*)(ws + (29u << 20));
    int*            CNT   = (int*)(ws + (66u << 20));

    // 2*XC = 262144 = 1024 * 256
    prep_kernel<<<1024, 256, 0, stream>>>(x, down_bias, XB, out);

    bin_kernel<<<768, 256, 0, stream>>>(
        up_row, up_col, up_val, gate_row, gate_col, gate_val,
        down_row, down_col, down_val, BANDS, CNT);

    build_kernel<<<768, 512, 0, stream>>>(BANDS, CNT, WUP, WGATE, WDOWN);

    gemm_upgate_kernel<<<dim3(HIDDEN_ / 128, TTOK_ / 64), 256, 0, stream>>>(
        XB, WUP, WGATE, up_bias, gate_bias, HID);

    gemm_down_kernel<<<dim3(DIM_ / 64, TTOK_ / 64, 4), 256, 0, stream>>>(
        HID, WDOWN, out);
}

// Round 7
// 140.175 us; speedup vs baseline: 1.7968x; 1.1003x over previous
//
#include <hip/hip_runtime.h>
#include <hip/hip_bf16.h>
#include <stdint.h>

// SparseSwiGLU on MI355X: fine-band radix densify -> bf16 weights -> MFMA GEMMs.
// R7: fused single-pass up+gate GEMM (512 blocks, 2/CU), prep fused into bin.
// T=512 tokens, DIM=1024, HIDDEN=4096, NNZ=262144 per matrix.
//
// Workspace layout (<= 67 MB):
//   [0,    8MB)  WUP    bf16 [4096][1024]   (B^T, K-contiguous)
//   [8MB, 16MB)  WGATE  bf16 [4096][1024]
//   [16MB,24MB)  WDOWN  bf16 [1024][4096]
//   [24MB,25MB)  XB     bf16 [512][1024]
//   [25MB,29MB)  HID    bf16 [512][4096]
//   [29MB,+36MB) BANDS  uint2[3][256 band][256 chunk][24 slot]
//   [66MB,+768K) CNT    int[3][256 band][256 chunk]

#define DIM_    1024
#define HIDDEN_ 4096
#define NNZ_    262144
#define TTOK_   512
#define PAD_    24              // 192 B segments, single-writer

typedef __attribute__((ext_vector_type(8))) short short8;
typedef __attribute__((ext_vector_type(4))) float float4v;

__device__ inline unsigned short f2bf(float f) {
    union { float f; unsigned int u; } c; c.f = f;
    unsigned int u = c.u;
    unsigned int r = u + 0x7fffu + ((u >> 16) & 1u);   // RNE
    return (unsigned short)(r >> 16);
}

__device__ inline void async16(const unsigned short* g, unsigned short* l) {
    __builtin_amdgcn_global_load_lds(
        (const __attribute__((address_space(1))) unsigned int*)g,
        (__attribute__((address_space(3))) unsigned int*)l, 16, 0, 0);
}

// ---------------------------------------------------------------- bin+prep
// Blocks [0,768): bin role — block = (mat, chunk of 1024 nnz), 256 bands/mat
//   (16 rows up/gate, 4 down). Entry (rrel<<12|col, valbits) into the block's
//   own 192B segment per band; counts -> CNT. Poisson(4)/bin, P(>24)~1e-11.
// Blocks [768,1024): prep role — x->bf16 and out = x + down_bias (4 float4/thr).
#define XC_ ((TTOK_ * DIM_) / 4)           // 131072 float4 units

__global__ __launch_bounds__(256) void bin_prep_kernel(
    const int* __restrict__ ur, const int* __restrict__ uc, const float* __restrict__ uv,
    const int* __restrict__ gr, const int* __restrict__ gc, const float* __restrict__ gv,
    const int* __restrict__ dr, const int* __restrict__ dc, const float* __restrict__ dv,
    const float* __restrict__ x, const float* __restrict__ down_bias,
    uint2* __restrict__ bands, int* __restrict__ cnt,
    unsigned short* __restrict__ xb, float* __restrict__ out) {
    const int b = blockIdx.x;
    const int t = threadIdx.x;
    if (b >= 768) {
        // ---- prep role: 256 blocks x 256 thr x 4 float4 units
        const unsigned int u0 = (b - 768) * 1024 + t * 4;
        #pragma unroll
        for (int q = 0; q < 4; ++q) {
            const unsigned int id = u0 + q;
            if (id < XC_) {
                float4 v = ((const float4*)x)[id];
                ushort4 o;
                o.x = f2bf(v.x); o.y = f2bf(v.y); o.z = f2bf(v.z); o.w = f2bf(v.w);
                ((ushort4*)xb)[id] = o;
            } else {
                const unsigned int i = id - XC_;
                float4 v = ((const float4*)x)[i];
                const int d = (i * 4) & (DIM_ - 1);
                const float4 bb = *(const float4*)(down_bias + d);
                float4 o;
                o.x = v.x + bb.x; o.y = v.y + bb.y; o.z = v.z + bb.z; o.w = v.w + bb.w;
                ((float4*)out)[i] = o;
            }
        }
        return;
    }
    // ---- bin role
    __shared__ int lcount[256];
    const int mat = b >> 8;          // 0 up, 1 gate, 2 down
    const int chunk = b & 255;
    const int*   rs = (mat == 0) ? ur : (mat == 1) ? gr : dr;
    const int*   cs = (mat == 0) ? uc : (mat == 1) ? gc : dc;
    const float* vs = (mat == 0) ? uv : (mat == 1) ? gv : dv;
    const int shift = (mat == 2) ? 2 : 4;   // rows/band: 4 (down), 16 (up/gate)
    const int rmask = (mat == 2) ? 3 : 15;
    lcount[t] = 0;
    __syncthreads();

    const int base = chunk * 1024 + t * 4;
    int4   r4 = *(const int4*)(rs + base);
    int4   c4 = *(const int4*)(cs + base);
    float4 v4 = *(const float4*)(vs + base);
    uint2* mbase = bands + mat * (256 * 256 * PAD_);
    int   rr[4] = {r4.x, r4.y, r4.z, r4.w};
    int   cc[4] = {c4.x, c4.y, c4.z, c4.w};
    float vv[4] = {v4.x, v4.y, v4.z, v4.w};
    #pragma unroll
    for (int j = 0; j < 4; ++j) {
        const int band = rr[j] >> shift;
        const int pos = atomicAdd(&lcount[band], 1);
        if (pos < PAD_) {
            uint2 e;
            e.x = ((unsigned int)(rr[j] & rmask) << 12) | (unsigned int)cc[j];
            e.y = __float_as_uint(vv[j]);
            mbase[(band * 256 + chunk) * PAD_ + pos] = e;
        }
    }
    __syncthreads();
    cnt[(mat * 256 + t) * 256 + chunk] = lcount[t];
}

// ---------------------------------------------------------------- build
// One block == one band (16 up/gate rows or 4 down rows; 64KB fp32 LDS).
// Half 0 loads slots 0..11 unconditionally (6 dwordx4, use guarded by count),
// half 1 handles the rare overflow tail. Streams bf16 rows out once.
__global__ __launch_bounds__(512) void build_kernel(
    const uint2* __restrict__ bands,
    const int* __restrict__ cnt,
    unsigned short* __restrict__ WUP,
    unsigned short* __restrict__ WGATE,
    unsigned short* __restrict__ WDOWN) {
    __shared__ float acc[16 * 1024];
    __shared__ int lcnt[256];
    const int b = blockIdx.x;
    const int t = threadIdx.x;
    const int mat = b >> 8;
    const int band = b & 255;
    unsigned int width;
    unsigned short* out;
    if (mat == 0)      { width = 1024; out = WUP + band * 16 * 1024; }
    else if (mat == 1) { width = 1024; out = WGATE + band * 16 * 1024; }
    else               { width = 4096; out = WDOWN + band * 4 * 4096; }

    for (int k = 0; k < 8; ++k)
        *(float4*)&acc[(k * 512 + t) * 4] = make_float4(0.f, 0.f, 0.f, 0.f);
    if (t < 256) lcnt[t] = cnt[(mat * 256 + band) * 256 + t];
    __syncthreads();

    const int chunk = t & 255;
    const int half = t >> 8;
    const uint2* seg = bands + (((mat * 256 + band) * 256) + chunk) * PAD_;
    const int c = lcnt[chunk];

    if (half == 0) {
        uint4 q[6];
        const uint4* sp = (const uint4*)seg;
        #pragma unroll
        for (int i = 0; i < 6; ++i) q[i] = sp[i];
        #pragma unroll
        for (int j = 0; j < 12; ++j) {
            const unsigned int ex = (j & 1) ? q[j >> 1].z : q[j >> 1].x;
            const unsigned int ey = (j & 1) ? q[j >> 1].w : q[j >> 1].y;
            if (j < c)
                atomicAdd(&acc[(ex >> 12) * width + (ex & 0xFFFu)],
                          __uint_as_float(ey));
        }
    } else {
        for (int j = 12; j < c && j < PAD_; ++j) {
            uint2 e = seg[j];
            atomicAdd(&acc[(e.x >> 12) * width + (e.x & 0xFFFu)],
                      __uint_as_float(e.y));
        }
    }
    __syncthreads();

    for (int k = 0; k < 8; ++k) {
        const int cc = (k * 512 + t) * 4;
        ushort4 o;
        o.x = f2bf(acc[cc]);     o.y = f2bf(acc[cc + 1]);
        o.z = f2bf(acc[cc + 2]); o.w = f2bf(acc[cc + 3]);
        *(ushort4*)(out + cc) = o;
    }
}

// ---------------------------------------------------------------- up+gate GEMM
// R7: single K-pass, both weight tiles staged per iter. Tile 64Mx64N,
// wave-tile 32x32, dual acc. Grid (4096/64, 512/64) = 512 blocks = 2/CU,
// 8 waves/CU (vs 4 before). Epilogue: silu(u+ub)*(g+gb) -> HID bf16.
__global__ __launch_bounds__(256) void gemm_upgate_kernel(
    const unsigned short* __restrict__ xb,      // [512][1024]
    const unsigned short* __restrict__ wup,     // [4096][1024]
    const unsigned short* __restrict__ wgate,   // [4096][1024]
    const float* __restrict__ up_bias,
    const float* __restrict__ gate_bias,
    unsigned short* __restrict__ hid) {         // [512][4096]
    __shared__ unsigned short sA[64 * 32];
    __shared__ unsigned short sBu[64 * 32];
    __shared__ unsigned short sBg[64 * 32];
    const int t = threadIdx.x;
    const int n0 = blockIdx.x * 64;
    const int m0 = blockIdx.y * 64;
    const int w = t >> 6, l = t & 63;
    const int wm = (w >> 1) * 32, wn = (w & 1) * 32;
    const int lr = l & 15, lkq = (l >> 4);

    float4v au[2][2], ag[2][2];
    for (int im = 0; im < 2; ++im)
        for (int in = 0; in < 2; ++in) {
            au[im][in] = float4v{0.f, 0.f, 0.f, 0.f};
            ag[im][in] = float4v{0.f, 0.f, 0.f, 0.f};
        }

    const int srow = t >> 2, scol = (t & 3) * 8;

    for (int k0 = 0; k0 < DIM_; k0 += 32) {
        async16(xb + (m0 + srow) * DIM_ + k0 + scol, &sA[t * 8]);
        async16(wup + (n0 + srow) * DIM_ + k0 + scol, &sBu[t * 8]);
        async16(wgate + (n0 + srow) * DIM_ + k0 + scol, &sBg[t * 8]);
        __syncthreads();
        short8 a[2], bu[2], bg[2];
        for (int im = 0; im < 2; ++im)
            a[im] = *(const short8*)&sA[(wm + im * 16 + lr) * 32 + lkq * 8];
        for (int in = 0; in < 2; ++in) {
            bu[in] = *(const short8*)&sBu[(wn + in * 16 + lr) * 32 + lkq * 8];
            bg[in] = *(const short8*)&sBg[(wn + in * 16 + lr) * 32 + lkq * 8];
        }
        for (int im = 0; im < 2; ++im)
            for (int in = 0; in < 2; ++in) {
                au[im][in] = __builtin_amdgcn_mfma_f32_16x16x32_bf16(
                    a[im], bu[in], au[im][in], 0, 0, 0);
                ag[im][in] = __builtin_amdgcn_mfma_f32_16x16x32_bf16(
                    a[im], bg[in], ag[im][in], 0, 0, 0);
            }
        __syncthreads();
    }

    for (int im = 0; im < 2; ++im) {
        for (int in = 0; in < 2; ++in) {
            const int n = n0 + wn + in * 16 + lr;
            const float ub = up_bias[n], gb = gate_bias[n];
            for (int r = 0; r < 4; ++r) {
                const int m = m0 + wm + im * 16 + lkq * 4 + r;
                const float u = au[im][in][r] + ub;
                const float g = ag[im][in][r] + gb;
                const float h = (u / (1.f + __expf(-u))) * g;
                hid[m * HIDDEN_ + n] = f2bf(h);
            }
        }
    }
}

// ---------------------------------------------------------------- down GEMM
// C[512][1024] tiles 64x64, split-K=4, atomicAdd epilogue onto d_out
// (pre-initialized to x + down_bias by prep role of bin_prep).
__global__ __launch_bounds__(256) void gemm_down_kernel(
    const unsigned short* __restrict__ hid,     // [512][4096]
    const unsigned short* __restrict__ wdown,   // [1024][4096]
    float* __restrict__ out) {                  // [512][1024]
    __shared__ unsigned short sA[64 * 32];
    __shared__ unsigned short sB[64 * 32];
    const int t = threadIdx.x;
    const int n0 = blockIdx.x * 64;
    const int m0 = blockIdx.y * 64;
    const int kb = blockIdx.z * 1024;
    const int w = t >> 6, l = t & 63;
    const int wm = (w >> 1) * 32, wn = (w & 1) * 32;
    const int lr = l & 15, lkq = (l >> 4);

    float4v acc[2][2];
    for (int im = 0; im < 2; ++im)
        for (int in = 0; in < 2; ++in)
            acc[im][in] = float4v{0.f, 0.f, 0.f, 0.f};

    const int srow = t >> 2, scol = (t & 3) * 8;

    for (int k0 = kb; k0 < kb + 1024; k0 += 32) {
        async16(hid + (m0 + srow) * HIDDEN_ + k0 + scol, &sA[t * 8]);
        async16(wdown + (n0 + srow) * HIDDEN_ + k0 + scol, &sB[t * 8]);
        __syncthreads();
        short8 a[2], b[2];
        for (int im = 0; im < 2; ++im)
            a[im] = *(const short8*)&sA[(wm + im * 16 + lr) * 32 + lkq * 8];
        for (int in = 0; in < 2; ++in)
            b[in] = *(const short8*)&sB[(wn + in * 16 + lr) * 32 + lkq * 8];
        for (int im = 0; im < 2; ++im)
            for (int in = 0; in < 2; ++in)
                acc[im][in] = __builtin_amdgcn_mfma_f32_16x16x32_bf16(
                    a[im], b[in], acc[im][in], 0, 0, 0);
        __syncthreads();
    }

    for (int im = 0; im < 2; ++im) {
        for (int in = 0; in < 2; ++in) {
            const int n = n0 + wn + in * 16 + lr;
            for (int r = 0; r < 4; ++r) {
                const int m = m0 + wm + im * 16 + lkq * 4 + r;
                atomicAdd(out + m * DIM_ + n, acc[im][in][r]);
            }
        }
    }
}

// ---------------------------------------------------------------- launch
extern "C" void kernel_launch(void* const* d_in, const int* in_sizes, int n_in,
                              void* d_out, int out_size, void* d_ws, size_t ws_size,
                              hipStream_t stream) {
    const float* x         = (const float*)d_in[0];
    const int*   up_row    = (const int*)d_in[1];
    const int*   up_col    = (const int*)d_in[2];
    const float* up_val    = (const float*)d_in[3];
    const float* up_bias   = (const float*)d_in[4];
    const int*   gate_row  = (const int*)d_in[5];
    const int*   gate_col  = (const int*)d_in[6];
    const float* gate_val  = (const float*)d_in[7];
    const float* gate_bias = (const float*)d_in[8];
    const int*   down_row  = (const int*)d_in[9];
    const int*   down_col  = (const int*)d_in[10];
    const float* down_val  = (const float*)d_in[11];
    const float* down_bias = (const float*)d_in[12];
    float* out = (float*)d_out;

    unsigned char* ws = (unsigned char*)d_ws;
    unsigned short* WUP   = (unsigned short*)(ws);
    unsigned short* WGATE = (unsigned short*)(ws + (8u << 20));
    unsigned short* WDOWN = (unsigned short*)(ws + (16u << 20));
    unsigned short* XB    = (unsigned short*)(ws + (24u << 20));
    unsigned short* HID   = (unsigned short*)(ws + (25u << 20));
    uint2*          BANDS = (uint2*)(ws + (29u << 20));
    int*            CNT   = (int*)(ws + (66u << 20));

    bin_prep_kernel<<<1024, 256, 0, stream>>>(
        up_row, up_col, up_val, gate_row, gate_col, gate_val,
        down_row, down_col, down_val, x, down_bias, BANDS, CNT, XB, out);

    build_kernel<<<768, 512, 0, stream>>>(BANDS, CNT, WUP, WGATE, WDOWN);

    gemm_upgate_kernel<<<dim3(HIDDEN_ / 64, TTOK_ / 64), 256, 0, stream>>>(
        XB, WUP, WGATE, up_bias, gate_bias, HID);

    gemm_down_kernel<<<dim3(DIM_ / 64, TTOK_ / 64, 4), 256, 0, stream>>>(
        HID, WDOWN, out);
}

// Round 8
// 138.331 us; speedup vs baseline: 1.8208x; 1.0133x over previous
//
#include <hip/hip_runtime.h>
#include <hip/hip_bf16.h>
#include <stdint.h>

// SparseSwiGLU on MI355X: fine-band radix densify -> bf16 weights -> MFMA GEMMs.
// R8: BK=64 K-loops (half the barrier drains) in both GEMMs; down split-K=8.
// T=512 tokens, DIM=1024, HIDDEN=4096, NNZ=262144 per matrix.
//
// Workspace layout (<= 67 MB):
//   [0,    8MB)  WUP    bf16 [4096][1024]   (B^T, K-contiguous)
//   [8MB, 16MB)  WGATE  bf16 [4096][1024]
//   [16MB,24MB)  WDOWN  bf16 [1024][4096]
//   [24MB,25MB)  XB     bf16 [512][1024]
//   [25MB,29MB)  HID    bf16 [512][4096]
//   [29MB,+36MB) BANDS  uint2[3][256 band][256 chunk][24 slot]
//   [66MB,+768K) CNT    int[3][256 band][256 chunk]

#define DIM_    1024
#define HIDDEN_ 4096
#define NNZ_    262144
#define TTOK_   512
#define PAD_    24              // 192 B segments, single-writer

typedef __attribute__((ext_vector_type(8))) short short8;
typedef __attribute__((ext_vector_type(4))) float float4v;

__device__ inline unsigned short f2bf(float f) {
    union { float f; unsigned int u; } c; c.f = f;
    unsigned int u = c.u;
    unsigned int r = u + 0x7fffu + ((u >> 16) & 1u);   // RNE
    return (unsigned short)(r >> 16);
}

__device__ inline void async16(const unsigned short* g, unsigned short* l) {
    __builtin_amdgcn_global_load_lds(
        (const __attribute__((address_space(1))) unsigned int*)g,
        (__attribute__((address_space(3))) unsigned int*)l, 16, 0, 0);
}

// ---------------------------------------------------------------- bin+prep
// Blocks [0,768): bin — block = (mat, chunk of 1024 nnz), 256 bands/mat
//   (16 rows up/gate, 4 down). Entry (rrel<<12|col, valbits) into the block's
//   own 192B segment per band; counts -> CNT. Poisson(4)/bin, P(>24)~1e-11.
// Blocks [768,1024): prep — x->bf16 and out = x + down_bias (4 float4/thr).
#define XC_ ((TTOK_ * DIM_) / 4)           // 131072 float4 units

__global__ __launch_bounds__(256) void bin_prep_kernel(
    const int* __restrict__ ur, const int* __restrict__ uc, const float* __restrict__ uv,
    const int* __restrict__ gr, const int* __restrict__ gc, const float* __restrict__ gv,
    const int* __restrict__ dr, const int* __restrict__ dc, const float* __restrict__ dv,
    const float* __restrict__ x, const float* __restrict__ down_bias,
    uint2* __restrict__ bands, int* __restrict__ cnt,
    unsigned short* __restrict__ xb, float* __restrict__ out) {
    const int b = blockIdx.x;
    const int t = threadIdx.x;
    if (b >= 768) {
        const unsigned int u0 = (b - 768) * 1024 + t * 4;
        #pragma unroll
        for (int q = 0; q < 4; ++q) {
            const unsigned int id = u0 + q;
            if (id < XC_) {
                float4 v = ((const float4*)x)[id];
                ushort4 o;
                o.x = f2bf(v.x); o.y = f2bf(v.y); o.z = f2bf(v.z); o.w = f2bf(v.w);
                ((ushort4*)xb)[id] = o;
            } else {
                const unsigned int i = id - XC_;
                float4 v = ((const float4*)x)[i];
                const int d = (i * 4) & (DIM_ - 1);
                const float4 bb = *(const float4*)(down_bias + d);
                float4 o;
                o.x = v.x + bb.x; o.y = v.y + bb.y; o.z = v.z + bb.z; o.w = v.w + bb.w;
                ((float4*)out)[i] = o;
            }
        }
        return;
    }
    __shared__ int lcount[256];
    const int mat = b >> 8;          // 0 up, 1 gate, 2 down
    const int chunk = b & 255;
    const int*   rs = (mat == 0) ? ur : (mat == 1) ? gr : dr;
    const int*   cs = (mat == 0) ? uc : (mat == 1) ? gc : dc;
    const float* vs = (mat == 0) ? uv : (mat == 1) ? gv : dv;
    const int shift = (mat == 2) ? 2 : 4;   // rows/band: 4 (down), 16 (up/gate)
    const int rmask = (mat == 2) ? 3 : 15;
    lcount[t] = 0;
    __syncthreads();

    const int base = chunk * 1024 + t * 4;
    int4   r4 = *(const int4*)(rs + base);
    int4   c4 = *(const int4*)(cs + base);
    float4 v4 = *(const float4*)(vs + base);
    uint2* mbase = bands + mat * (256 * 256 * PAD_);
    int   rr[4] = {r4.x, r4.y, r4.z, r4.w};
    int   cc[4] = {c4.x, c4.y, c4.z, c4.w};
    float vv[4] = {v4.x, v4.y, v4.z, v4.w};
    #pragma unroll
    for (int j = 0; j < 4; ++j) {
        const int band = rr[j] >> shift;
        const int pos = atomicAdd(&lcount[band], 1);
        if (pos < PAD_) {
            uint2 e;
            e.x = ((unsigned int)(rr[j] & rmask) << 12) | (unsigned int)cc[j];
            e.y = __float_as_uint(vv[j]);
            mbase[(band * 256 + chunk) * PAD_ + pos] = e;
        }
    }
    __syncthreads();
    cnt[(mat * 256 + t) * 256 + chunk] = lcount[t];
}

// ---------------------------------------------------------------- build
// One block == one band (16 up/gate rows or 4 down rows; 64KB fp32 LDS).
// Half 0 loads slots 0..11 unconditionally (6 dwordx4, use guarded by count),
// half 1 handles the rare overflow tail. Streams bf16 rows out once.
__global__ __launch_bounds__(512) void build_kernel(
    const uint2* __restrict__ bands,
    const int* __restrict__ cnt,
    unsigned short* __restrict__ WUP,
    unsigned short* __restrict__ WGATE,
    unsigned short* __restrict__ WDOWN) {
    __shared__ float acc[16 * 1024];
    __shared__ int lcnt[256];
    const int b = blockIdx.x;
    const int t = threadIdx.x;
    const int mat = b >> 8;
    const int band = b & 255;
    unsigned int width;
    unsigned short* out;
    if (mat == 0)      { width = 1024; out = WUP + band * 16 * 1024; }
    else if (mat == 1) { width = 1024; out = WGATE + band * 16 * 1024; }
    else               { width = 4096; out = WDOWN + band * 4 * 4096; }

    for (int k = 0; k < 8; ++k)
        *(float4*)&acc[(k * 512 + t) * 4] = make_float4(0.f, 0.f, 0.f, 0.f);
    if (t < 256) lcnt[t] = cnt[(mat * 256 + band) * 256 + t];
    __syncthreads();

    const int chunk = t & 255;
    const int half = t >> 8;
    const uint2* seg = bands + (((mat * 256 + band) * 256) + chunk) * PAD_;
    const int c = lcnt[chunk];

    if (half == 0) {
        uint4 q[6];
        const uint4* sp = (const uint4*)seg;
        #pragma unroll
        for (int i = 0; i < 6; ++i) q[i] = sp[i];
        #pragma unroll
        for (int j = 0; j < 12; ++j) {
            const unsigned int ex = (j & 1) ? q[j >> 1].z : q[j >> 1].x;
            const unsigned int ey = (j & 1) ? q[j >> 1].w : q[j >> 1].y;
            if (j < c)
                atomicAdd(&acc[(ex >> 12) * width + (ex & 0xFFFu)],
                          __uint_as_float(ey));
        }
    } else {
        for (int j = 12; j < c && j < PAD_; ++j) {
            uint2 e = seg[j];
            atomicAdd(&acc[(e.x >> 12) * width + (e.x & 0xFFFu)],
                      __uint_as_float(e.y));
        }
    }
    __syncthreads();

    for (int k = 0; k < 8; ++k) {
        const int cc = (k * 512 + t) * 4;
        ushort4 o;
        o.x = f2bf(acc[cc]);     o.y = f2bf(acc[cc + 1]);
        o.z = f2bf(acc[cc + 2]); o.w = f2bf(acc[cc + 3]);
        *(ushort4*)(out + cc) = o;
    }
}

// ---------------------------------------------------------------- up+gate GEMM
// R8: BK=64 (two k-chunked 64x32 LDS sub-tiles per buffer -> lane-contiguous
// global_load_lds + proven 64B-row ds_reads), 16 MFMA per barrier pair.
// Tile 64Mx64N, wave-tile 32x32, dual acc, grid 512 = 2 blocks/CU.
__global__ __launch_bounds__(256) void gemm_upgate_kernel(
    const unsigned short* __restrict__ xb,      // [512][1024]
    const unsigned short* __restrict__ wup,     // [4096][1024]
    const unsigned short* __restrict__ wgate,   // [4096][1024]
    const float* __restrict__ up_bias,
    const float* __restrict__ gate_bias,
    unsigned short* __restrict__ hid) {         // [512][4096]
    __shared__ unsigned short sA[2 * 64 * 32];
    __shared__ unsigned short sBu[2 * 64 * 32];
    __shared__ unsigned short sBg[2 * 64 * 32];
    const int t = threadIdx.x;
    const int n0 = blockIdx.x * 64;
    const int m0 = blockIdx.y * 64;
    const int w = t >> 6, l = t & 63;
    const int wm = (w >> 1) * 32, wn = (w & 1) * 32;
    const int lr = l & 15, lkq = (l >> 4);

    float4v au[2][2], ag[2][2];
    for (int im = 0; im < 2; ++im)
        for (int in = 0; in < 2; ++in) {
            au[im][in] = float4v{0.f, 0.f, 0.f, 0.f};
            ag[im][in] = float4v{0.f, 0.f, 0.f, 0.f};
        }

    const int srow = t >> 2, scol = (t & 3) * 8;
    const unsigned short* gA  = xb    + (m0 + srow) * DIM_ + scol;
    const unsigned short* gBu = wup   + (n0 + srow) * DIM_ + scol;
    const unsigned short* gBg = wgate + (n0 + srow) * DIM_ + scol;

    for (int k0 = 0; k0 < DIM_; k0 += 64) {
        async16(gA + k0,       &sA[t * 8]);
        async16(gA + k0 + 32,  &sA[2048 + t * 8]);
        async16(gBu + k0,      &sBu[t * 8]);
        async16(gBu + k0 + 32, &sBu[2048 + t * 8]);
        async16(gBg + k0,      &sBg[t * 8]);
        async16(gBg + k0 + 32, &sBg[2048 + t * 8]);
        __syncthreads();
        #pragma unroll
        for (int kk = 0; kk < 2; ++kk) {
            const int kb = kk * 2048 + lkq * 8;
            short8 a[2], bu[2], bg[2];
            for (int im = 0; im < 2; ++im)
                a[im] = *(const short8*)&sA[kb + (wm + im * 16 + lr) * 32];
            for (int in = 0; in < 2; ++in) {
                bu[in] = *(const short8*)&sBu[kb + (wn + in * 16 + lr) * 32];
                bg[in] = *(const short8*)&sBg[kb + (wn + in * 16 + lr) * 32];
            }
            for (int im = 0; im < 2; ++im)
                for (int in = 0; in < 2; ++in) {
                    au[im][in] = __builtin_amdgcn_mfma_f32_16x16x32_bf16(
                        a[im], bu[in], au[im][in], 0, 0, 0);
                    ag[im][in] = __builtin_amdgcn_mfma_f32_16x16x32_bf16(
                        a[im], bg[in], ag[im][in], 0, 0, 0);
                }
        }
        __syncthreads();
    }

    for (int im = 0; im < 2; ++im) {
        for (int in = 0; in < 2; ++in) {
            const int n = n0 + wn + in * 16 + lr;
            const float ub = up_bias[n], gb = gate_bias[n];
            for (int r = 0; r < 4; ++r) {
                const int m = m0 + wm + im * 16 + lkq * 4 + r;
                const float u = au[im][in][r] + ub;
                const float g = ag[im][in][r] + gb;
                const float h = (u / (1.f + __expf(-u))) * g;
                hid[m * HIDDEN_ + n] = f2bf(h);
            }
        }
    }
}

// ---------------------------------------------------------------- down GEMM
// R8: BK=64, split-K=8 (grid 1024 = 4 blocks/CU). atomicAdd epilogue onto
// d_out (pre-initialized to x + down_bias by prep role of bin_prep).
__global__ __launch_bounds__(256) void gemm_down_kernel(
    const unsigned short* __restrict__ hid,     // [512][4096]
    const unsigned short* __restrict__ wdown,   // [1024][4096]
    float* __restrict__ out) {                  // [512][1024]
    __shared__ unsigned short sA[2 * 64 * 32];
    __shared__ unsigned short sB[2 * 64 * 32];
    const int t = threadIdx.x;
    const int n0 = blockIdx.x * 64;
    const int m0 = blockIdx.y * 64;
    const int kb0 = blockIdx.z * 512;
    const int w = t >> 6, l = t & 63;
    const int wm = (w >> 1) * 32, wn = (w & 1) * 32;
    const int lr = l & 15, lkq = (l >> 4);

    float4v acc[2][2];
    for (int im = 0; im < 2; ++im)
        for (int in = 0; in < 2; ++in)
            acc[im][in] = float4v{0.f, 0.f, 0.f, 0.f};

    const int srow = t >> 2, scol = (t & 3) * 8;
    const unsigned short* gA = hid   + (m0 + srow) * HIDDEN_ + scol;
    const unsigned short* gB = wdown + (n0 + srow) * HIDDEN_ + scol;

    for (int k0 = kb0; k0 < kb0 + 512; k0 += 64) {
        async16(gA + k0,      &sA[t * 8]);
        async16(gA + k0 + 32, &sA[2048 + t * 8]);
        async16(gB + k0,      &sB[t * 8]);
        async16(gB + k0 + 32, &sB[2048 + t * 8]);
        __syncthreads();
        #pragma unroll
        for (int kk = 0; kk < 2; ++kk) {
            const int kb = kk * 2048 + lkq * 8;
            short8 a[2], b[2];
            for (int im = 0; im < 2; ++im)
                a[im] = *(const short8*)&sA[kb + (wm + im * 16 + lr) * 32];
            for (int in = 0; in < 2; ++in)
                b[in] = *(const short8*)&sB[kb + (wn + in * 16 + lr) * 32];
            for (int im = 0; im < 2; ++im)
                for (int in = 0; in < 2; ++in)
                    acc[im][in] = __builtin_amdgcn_mfma_f32_16x16x32_bf16(
                        a[im], b[in], acc[im][in], 0, 0, 0);
        }
        __syncthreads();
    }

    for (int im = 0; im < 2; ++im) {
        for (int in = 0; in < 2; ++in) {
            const int n = n0 + wn + in * 16 + lr;
            for (int r = 0; r < 4; ++r) {
                const int m = m0 + wm + im * 16 + lkq * 4 + r;
                atomicAdd(out + m * DIM_ + n, acc[im][in][r]);
            }
        }
    }
}

// ---------------------------------------------------------------- launch
extern "C" void kernel_launch(void* const* d_in, const int* in_sizes, int n_in,
                              void* d_out, int out_size, void* d_ws, size_t ws_size,
                              hipStream_t stream) {
    const float* x         = (const float*)d_in[0];
    const int*   up_row    = (const int*)d_in[1];
    const int*   up_col    = (const int*)d_in[2];
    const float* up_val    = (const float*)d_in[3];
    const float* up_bias   = (const float*)d_in[4];
    const int*   gate_row  = (const int*)d_in[5];
    const int*   gate_col  = (const int*)d_in[6];
    const float* gate_val  = (const float*)d_in[7];
    const float* gate_bias = (const float*)d_in[8];
    const int*   down_row  = (const int*)d_in[9];
    const int*   down_col  = (const int*)d_in[10];
    const float* down_val  = (const float*)d_in[11];
    const float* down_bias = (const float*)d_in[12];
    float* out = (float*)d_out;

    unsigned char* ws = (unsigned char*)d_ws;
    unsigned short* WUP   = (unsigned short*)(ws);
    unsigned short* WGATE = (unsigned short*)(ws + (8u << 20));
    unsigned short* WDOWN = (unsigned short*)(ws + (16u << 20));
    unsigned short* XB    = (unsigned short*)(ws + (24u << 20));
    unsigned short* HID   = (unsigned short*)(ws + (25u << 20));
    uint2*          BANDS = (uint2*)(ws + (29u << 20));
    int*            CNT   = (int*)(ws + (66u << 20));

    bin_prep_kernel<<<1024, 256, 0, stream>>>(
        up_row, up_col, up_val, gate_row, gate_col, gate_val,
        down_row, down_col, down_val, x, down_bias, BANDS, CNT, XB, out);

    build_kernel<<<768, 512, 0, stream>>>(BANDS, CNT, WUP, WGATE, WDOWN);

    gemm_upgate_kernel<<<dim3(HIDDEN_ / 64, TTOK_ / 64), 256, 0, stream>>>(
        XB, WUP, WGATE, up_bias, gate_bias, HID);

    gemm_down_kernel<<<dim3(DIM_ / 64, TTOK_ / 64, 8), 256, 0, stream>>>(
        HID, WDOWN, out);
}